// Round 7
// baseline (179.899 us; speedup 1.0000x reference)
//
#include <hip/hip_runtime.h>
#include <math.h>

// Problem constants: B=2, L=1024, D=512, H=8, h=64, K=H=8, EPS=1e-5
// R7: 3-kernel hybrid.  Lessons from the mega arc (R3-R6): grid barriers cost
// ~12us regardless of fence strategy; write-through-everything forces L3-lat
// reads (+30-40us).  So: launch boundaries where traffic is big (Qb/UB2/UB/
// WOT plain stores, flushed by dispatch-end release), fence-free in-kernel
// barriers where traffic is small (WT/GL via sc0sc1 write-through; AF via
// device-coherent atomicAdd).  Deleted vs R1: XB+castx (qkv casts x inline),
// WGB (conv casts wg inline), AP+reduce (amat atomicAdds into AF).
//   k1: packw -> bar -> qkv          (WT sc; WOT/Qb/UB2 plain)
//   k2: conv+gate -> bar -> amat -> bar -> ctxt   (GL sc; AF atomic; UB plain)
//   k3: out = UB @ WOT^T + bo
// absmax may shift ~ulp vs 0.002075 (AF atomic summation order).

typedef __attribute__((ext_vector_type(8))) short short8;
typedef __attribute__((ext_vector_type(4))) float floatx4;
typedef __attribute__((ext_vector_type(2))) unsigned int uintx2;

__device__ __forceinline__ unsigned short f2bf(float f) {
    unsigned int u = __float_as_uint(f);
    unsigned int r = (u + 0x7FFFu + ((u >> 16) & 1u)) >> 16;   // RNE
    return (unsigned short)r;
}

// Device-coherent (cross-XCD visible) stores for small cross-barrier buffers.
__device__ __forceinline__ void stg_sc1(void* p, float v) {
    asm volatile("global_store_dword %0, %1, off sc0 sc1"
                 :: "v"(p), "v"(v) : "memory");
}
__device__ __forceinline__ void stg_sc2(void* p, uintx2 v) {
    asm volatile("global_store_dwordx2 %0, %1, off sc0 sc1"
                 :: "v"(p), "v"(v) : "memory");
}

// Fence-free grid barrier: drain this wave's VMEM (sc stores/atomics are at
// the coherence point once vmcnt retires; plain stores are in L2 — their
// consumers are beyond a launch boundary), then arrive+spin.
__device__ __forceinline__ void gbar(unsigned int* cnt) {
    asm volatile("s_waitcnt vmcnt(0)" ::: "memory");
    __syncthreads();
    if (threadIdx.x == 0) {
        __hip_atomic_fetch_add(cnt, 1u, __ATOMIC_RELAXED,
                               __HIP_MEMORY_SCOPE_AGENT);
        while (__hip_atomic_load(cnt, __ATOMIC_RELAXED,
                                 __HIP_MEMORY_SCOPE_AGENT) < 256u)
            __builtin_amdgcn_s_sleep(4);
    }
    __syncthreads();
    asm volatile("" ::: "memory");
}

// ---------------------------------------------------------------------------
// K1: phase0 packw (WT sc-stored, WOT plain) -> gbar -> qkv (A cast inline
// from fp32 x).  grid 256, 256 thr.
// ---------------------------------------------------------------------------
__global__ __launch_bounds__(256) void k_qkvw(
    const float* __restrict__ x,
    const float* __restrict__ wq, const float* __restrict__ wk,
    const float* __restrict__ wv, const float* __restrict__ wo,
    const float* __restrict__ bq, const float* __restrict__ bk,
    const float* __restrict__ bv,
    unsigned short* __restrict__ WT, unsigned short* __restrict__ WOT,
    float* __restrict__ Qb, unsigned short* __restrict__ UB2,
    unsigned int* __restrict__ CNT)
{
    const int blk = blockIdx.x;
    const int tid = threadIdx.x;
    const int lane = tid & 63, wave = tid >> 6;
    const int qd = lane >> 4, ln = lane & 15;

    __shared__ __align__(16) unsigned char arena[27648];  // max(sf, As+Bs)

    // ---- phase 0: packw (one 64x64 transpose+cast unit per block) ----
    {
        float (*sf)[65] = (float(*)[65])arena;   // 16900 B < 27648
        const int t = blk;
        const float* src; unsigned short* dst; int n0p, c0, k0p, isWT;
        if (t < 192) {
            int nt = t >> 3, kt = t & 7;
            n0p = nt * 64; k0p = kt * 64;
            int z = n0p >> 9; c0 = n0p & 511;
            src = (z == 0) ? wq : (z == 1) ? wk : wv;
            dst = WT; isWT = 1;
        } else {
            int u = t - 192; int nt = u >> 3, kt = u & 7;
            n0p = nt * 64; c0 = n0p; k0p = kt * 64;
            src = wo; dst = WOT; isWT = 0;
        }
        const int rr = tid >> 4, c4 = tid & 15;
        #pragma unroll
        for (int g = 0; g < 4; ++g) {
            int r = g*16 + rr;
            float4 v = *(const float4*)&src[(size_t)(k0p + r)*512 + c0 + c4*4];
            sf[r][c4*4+0]=v.x; sf[r][c4*4+1]=v.y; sf[r][c4*4+2]=v.z; sf[r][c4*4+3]=v.w;
        }
        __syncthreads();
        #pragma unroll
        for (int g = 0; g < 4; ++g) {
            int c = g*16 + rr;
            int kk = c4*4;
            uintx2 o;
            o.x = f2bf(sf[kk+0][c]) | ((unsigned)f2bf(sf[kk+1][c]) << 16);
            o.y = f2bf(sf[kk+2][c]) | ((unsigned)f2bf(sf[kk+3][c]) << 16);
            void* p = (void*)&dst[(size_t)(n0p + c)*512 + k0p + kk];
            if (isWT) stg_sc2(p, o);
            else      *(uintx2*)p = o;
        }
        __syncthreads();
    }
    gbar(CNT + 0);

    // ---- phase 1: qkv.  384 tiles (128m x 64n); blocks 0-127 do two. ----
    {
        unsigned short* As = (unsigned short*)arena;            // 128*72
        unsigned short* Bs = (unsigned short*)(arena + 18432);  // 64*72
        const int wm = wave * 32;
        const uint4* Bg = (const uint4*)WT;
        for (int t = blk; t < 384; t += 256) {
            const int m0 = (t / 24) * 128;
            const int n0 = (t % 24) * 64;

            floatx4 acc[2][4];
            #pragma unroll
            for (int i = 0; i < 2; ++i)
                #pragma unroll
                for (int j = 0; j < 4; ++j)
                    acc[i][j] = (floatx4){0.f, 0.f, 0.f, 0.f};

            for (int k0 = 0; k0 < 512; k0 += 64) {
                #pragma unroll
                for (int s = 0; s < 4; ++s) {       // A: inline cast from x
                    int idx = s*256 + tid;
                    int r = idx >> 3, cp = idx & 7;
                    const float* xs = &x[(size_t)(m0 + r)*512 + k0 + cp*8];
                    float4 a = *(const float4*)xs;
                    float4 b = *(const float4*)(xs + 4);
                    uint4 o;
                    o.x = f2bf(a.x) | ((unsigned)f2bf(a.y) << 16);
                    o.y = f2bf(a.z) | ((unsigned)f2bf(a.w) << 16);
                    o.z = f2bf(b.x) | ((unsigned)f2bf(b.y) << 16);
                    o.w = f2bf(b.z) | ((unsigned)f2bf(b.w) << 16);
                    *(uint4*)&As[r*72 + cp*8] = o;
                }
                #pragma unroll
                for (int s = 0; s < 2; ++s) {
                    int idx = s*256 + tid;
                    int r = idx >> 3, cp = idx & 7;
                    uint4 vb = Bg[(size_t)(n0 + r)*64 + (k0 >> 3) + cp];
                    *(uint4*)&Bs[r*72 + cp*8] = vb;
                }
                __syncthreads();
                short8 af0[2], af1[2], bf0[4], bf1[4];
                #pragma unroll
                for (int i = 0; i < 2; ++i) {
                    af0[i] = *(const short8*)&As[(wm + i*16 + ln)*72 + qd*8];
                    af1[i] = *(const short8*)&As[(wm + i*16 + ln)*72 + 32 + qd*8];
                }
                #pragma unroll
                for (int i = 0; i < 4; ++i) {
                    bf0[i] = *(const short8*)&Bs[(i*16 + ln)*72 + qd*8];
                    bf1[i] = *(const short8*)&Bs[(i*16 + ln)*72 + 32 + qd*8];
                }
                #pragma unroll
                for (int mi = 0; mi < 2; ++mi)
                    #pragma unroll
                    for (int ni = 0; ni < 4; ++ni) {
                        acc[mi][ni] = __builtin_amdgcn_mfma_f32_16x16x32_bf16(
                            af0[mi], bf0[ni], acc[mi][ni], 0, 0, 0);
                        acc[mi][ni] = __builtin_amdgcn_mfma_f32_16x16x32_bf16(
                            af1[mi], bf1[ni], acc[mi][ni], 0, 0, 0);
                    }
                __syncthreads();
            }

            const int z = n0 >> 9;
            if (z == 0) {
                #pragma unroll
                for (int mi = 0; mi < 2; ++mi) {
                    #pragma unroll
                    for (int ni = 0; ni < 4; ++ni) {
                        int c = (n0 + ni*16 + ln) & 511;
                        int head = c >> 6, dd = c & 63;
                        float bb = bq[c];
                        #pragma unroll
                        for (int reg = 0; reg < 4; ++reg) {
                            int row = m0 + wm + mi*16 + qd*4 + reg;
                            int b = row >> 10, l = row & 1023;
                            Qb[(size_t)((b*8 + head)*1024 + l)*64 + dd] =
                                acc[mi][ni][reg] + bb;
                        }
                    }
                }
            } else {
                const float scale = (z == 1) ? 0.125f : 1.0f;
                const float* bias = (z == 1) ? bk : bv;
                unsigned short* dst = UB2 + (size_t)(z-1) * 16 * 64 * 1024;
                #pragma unroll
                for (int mi = 0; mi < 2; ++mi) {
                    #pragma unroll
                    for (int ni = 0; ni < 4; ++ni) {
                        int c = (n0 + ni*16 + ln) & 511;
                        int head = c >> 6, dd = c & 63;
                        float bb = bias[c];
                        int row0 = m0 + wm + mi*16 + qd*4;
                        int b = row0 >> 10, l0 = row0 & 1023;
                        ushort4 o;
                        o.x = f2bf((acc[mi][ni][0] + bb) * scale);
                        o.y = f2bf((acc[mi][ni][1] + bb) * scale);
                        o.z = f2bf((acc[mi][ni][2] + bb) * scale);
                        o.w = f2bf((acc[mi][ni][3] + bb) * scale);
                        *(ushort4*)&dst[((size_t)((b*8 + head)*64) + dd)*1024 + l0] = o;
                    }
                }
            }
        }
    }
}

// ---------------------------------------------------------------------------
// K2: conv+gate -> gbar -> amat (atomicAdd -> AF) -> gbar -> ctxt.
// block (bh = blk&15, it = blk>>4).  grid 256, 256 thr.
// ---------------------------------------------------------------------------
__global__ __launch_bounds__(256) void k_core(
    const float* __restrict__ sb, const float* __restrict__ wgw,
    const float* __restrict__ wgbias,
    const unsigned short* __restrict__ UB2, const float* __restrict__ Qb,
    float* __restrict__ GL, float* __restrict__ AF,
    unsigned short* __restrict__ UB,
    unsigned int* __restrict__ CNT)
{
    const int blk = blockIdx.x;
    const int tid = threadIdx.x;
    const int lane = tid & 63, wave = tid >> 6;
    const int qd = lane >> 4, ln = lane & 15;
    const int tx = tid & 15, ty = tid >> 4;
    const int bh = blk & 15, h = bh & 7;
    const int it = blk >> 4, t0 = it * 64;

    __shared__ __align__(16) unsigned char arena[55552];
    float (*kts)[68] = (float(*)[68])arena;
    float (*vts)[68] = (float(*)[68])(arena + 17408);

    // ---- phase A: conv (k and v) + gate ----
    {
        unsigned short* revf = (unsigned short*)(arena + 34816);
        unsigned short* Bk = (unsigned short*)(arena + 37120);
        unsigned short* Bv = (unsigned short*)(arena + 46336);

        for (int i = tid; i < 1152; i += 256) {
            int d = 1087 - i;
            revf[i] = (d >= 0 && d < 1024) ? f2bf(sb[d*8 + h]) : (unsigned short)0;
        }

        const uint4* Bg = (const uint4*)UB2;
        const size_t bk_base = (size_t)bh * 8192;
        const size_t bv_base = (size_t)(16 + bh) * 8192;

        floatx4 acck[4], accv[4];
        #pragma unroll
        for (int i = 0; i < 4; ++i) {
            acck[i] = (floatx4){0.f,0.f,0.f,0.f};
            accv[i] = (floatx4){0.f,0.f,0.f,0.f};
        }

        const int kend = t0 + 64;
        const int arow = 1087 - t0 - (wave*16 + ln);
        for (int k0 = 0; k0 < kend; k0 += 64) {
            #pragma unroll
            for (int s = 0; s < 2; ++s) {
                int idx = s*256 + tid;
                int r = idx >> 3, cp = idx & 7;
                *(uint4*)&Bk[r*72 + cp*8] = Bg[bk_base + (size_t)r*128 + (k0 >> 3) + cp];
                *(uint4*)&Bv[r*72 + cp*8] = Bg[bv_base + (size_t)r*128 + (k0 >> 3) + cp];
            }
            __syncthreads();                   // also covers revf on first iter
            const int ab = arow + k0 + qd*8;
            short8 a0, a1;
            #pragma unroll
            for (int j = 0; j < 8; ++j) {
                a0[j] = (short)revf[ab + j];
                a1[j] = (short)revf[ab + 32 + j];
            }
            #pragma unroll
            for (int ni = 0; ni < 4; ++ni) {
                short8 kb0 = *(const short8*)&Bk[(ni*16 + ln)*72 + qd*8];
                short8 kb1 = *(const short8*)&Bk[(ni*16 + ln)*72 + 32 + qd*8];
                short8 vb0 = *(const short8*)&Bv[(ni*16 + ln)*72 + qd*8];
                short8 vb1 = *(const short8*)&Bv[(ni*16 + ln)*72 + 32 + qd*8];
                acck[ni] = __builtin_amdgcn_mfma_f32_16x16x32_bf16(a0, kb0, acck[ni], 0, 0, 0);
                acck[ni] = __builtin_amdgcn_mfma_f32_16x16x32_bf16(a1, kb1, acck[ni], 0, 0, 0);
                accv[ni] = __builtin_amdgcn_mfma_f32_16x16x32_bf16(a0, vb0, accv[ni], 0, 0, 0);
                accv[ni] = __builtin_amdgcn_mfma_f32_16x16x32_bf16(a1, vb1, accv[ni], 0, 0, 0);
            }
            __syncthreads();
        }

        // epilogue: conv tiles -> LDS (persist), KCb bf16 -> Bk, Wgb -> Bv
        #pragma unroll
        for (int ni = 0; ni < 4; ++ni)
            #pragma unroll
            for (int reg = 0; reg < 4; ++reg) {
                int row = wave*16 + qd*4 + reg;
                kts[row][ni*16 + ln] = acck[ni][reg];
                vts[row][ni*16 + ln] = accv[ni][reg];
                Bk[row*72 + ni*16 + ln] = f2bf(acck[ni][reg]);
            }
        #pragma unroll
        for (int s = 0; s < 2; ++s) {          // Wgb inline cast from wg fp32
            int idx = s*256 + tid;
            int r = idx >> 3, cp = idx & 7;
            const float* ws2 = &wgw[r*64 + cp*8];
            float4 a = *(const float4*)ws2;
            float4 b = *(const float4*)(ws2 + 4);
            uint4 o;
            o.x = f2bf(a.x) | ((unsigned)f2bf(a.y) << 16);
            o.y = f2bf(a.z) | ((unsigned)f2bf(a.w) << 16);
            o.z = f2bf(b.x) | ((unsigned)f2bf(b.y) << 16);
            o.w = f2bf(b.z) | ((unsigned)f2bf(b.w) << 16);
            *(uint4*)&Bv[r*72 + cp*8] = o;
        }
        __syncthreads();

        floatx4 T[4];
        #pragma unroll
        for (int mt = 0; mt < 4; ++mt) T[mt] = (floatx4){0.f,0.f,0.f,0.f};
        #pragma unroll
        for (int k0g = 0; k0g < 64; k0g += 32) {
            short8 a = *(const short8*)&Bk[(wave*16 + ln)*72 + k0g + qd*8];
            #pragma unroll
            for (int mt = 0; mt < 4; ++mt) {
                short8 b = *(const short8*)&Bv[(mt*16 + ln)*72 + k0g + qd*8];
                T[mt] = __builtin_amdgcn_mfma_f32_16x16x32_bf16(a, b, T[mt], 0, 0, 0);
            }
        }

        float part[4] = {0.f, 0.f, 0.f, 0.f};
        #pragma unroll
        for (int mt = 0; mt < 4; ++mt)
            #pragma unroll
            for (int reg = 0; reg < 4; ++reg)
                part[reg] += T[mt][reg] * accv[mt][reg];
        #pragma unroll
        for (int reg = 0; reg < 4; ++reg) {
            part[reg] += __shfl_xor(part[reg], 1);
            part[reg] += __shfl_xor(part[reg], 2);
            part[reg] += __shfl_xor(part[reg], 4);
            part[reg] += __shfl_xor(part[reg], 8);
        }
        if (ln == 0) {
            const float wb0 = wgbias[0];
            #pragma unroll
            for (int reg = 0; reg < 4; ++reg) {
                int l = t0 + wave*16 + qd*4 + reg;
                float s = part[reg] + wb0;
                float rr = fmaxf(s, 0.0f);
                stg_sc1((void*)&GL[bh*1024 + l], rr*rr + 1e-5f);
            }
        }
    }
    gbar(CNT + 0);

    // ---- phase B: gate scan + A_part from in-LDS conv tiles -> atomic AF ----
    {
        float* wfull = (float*)(arena + 34816);
        float* scanA = (float*)(arena + 38912);
        float* scanB = (float*)(arena + 38928);

        {
            const float4 g4 = ((const float4*)(GL + bh*1024))[tid];
            float g[4] = {g4.x, g4.y, g4.z, g4.w};
            float p[4];
            p[0]=g[0]; p[1]=p[0]+g[1]; p[2]=p[1]+g[2]; p[3]=p[2]+g[3];
            float xs = p[3];
            #pragma unroll
            for (int off = 1; off < 64; off <<= 1) {
                float t = __shfl_up(xs, off);
                if (lane >= off) xs += t;
            }
            if (lane == 63) scanA[wave] = xs;
            __syncthreads();
            float wb = 0.f;
            #pragma unroll
            for (int wv2 = 0; wv2 < 4; ++wv2) wb += (wv2 < wave) ? scanA[wv2] : 0.f;
            const float base = wb + xs - p[3];
            float r[4], pr[4];
            #pragma unroll
            for (int u = 0; u < 4; ++u) r[u] = 1.0f / (base + p[u] + 1e-5f);
            pr[0]=r[0]; pr[1]=pr[0]+r[1]; pr[2]=pr[1]+r[2]; pr[3]=pr[2]+r[3];
            float y = pr[3];
            #pragma unroll
            for (int off = 1; off < 64; off <<= 1) {
                float t = __shfl_up(y, off);
                if (lane >= off) y += t;
            }
            if (lane == 63) scanB[wave] = y;
            __syncthreads();
            float rb = 0.f, Rtot = 0.f;
            #pragma unroll
            for (int wv2 = 0; wv2 < 4; ++wv2) {
                rb   += (wv2 < wave) ? scanB[wv2] : 0.f;
                Rtot += scanB[wv2];
            }
            const float baser = rb + y - pr[3];
            wfull[tid*4+0] = g[0] * (Rtot - (baser + pr[0]) + r[0]);
            wfull[tid*4+1] = g[1] * (Rtot - (baser + pr[1]) + r[1]);
            wfull[tid*4+2] = g[2] * (Rtot - (baser + pr[2]) + r[2]);
            wfull[tid*4+3] = g[3] * (Rtot - (baser + pr[3]) + r[3]);
        }
        __syncthreads();

        float acc[4][4] = {};
        #pragma unroll 16
        for (int jj = 0; jj < 64; ++jj) {
            float wj = wfull[t0 + jj];
            float4 av = *(const float4*)&vts[jj][ty*4];
            float a[4] = { av.x*wj, av.y*wj, av.z*wj, av.w*wj };
            float4 b4 = *(const float4*)&kts[jj][tx*4];
            float bb[4] = {b4.x, b4.y, b4.z, b4.w};
            #pragma unroll
            for (int ii = 0; ii < 4; ++ii)
                #pragma unroll
                for (int jc = 0; jc < 4; ++jc)
                    acc[ii][jc] += a[ii] * bb[jc];
        }
        float* af = AF + (size_t)bh * 4096;
        #pragma unroll
        for (int i = 0; i < 4; ++i)
            #pragma unroll
            for (int jc = 0; jc < 4; ++jc)
                atomicAdd(&af[(ty*4+i)*64 + tx*4 + jc], acc[i][jc]);
    }
    gbar(CNT + 64);

    // ---- phase C: ctxt = q @ AF, row-normalize, bf16 -> UB ----
    {
        float (*qs)[20]   = (float(*)[20])arena;
        float (*As16)[68] = (float(*)[68])(arena + 5120);
        float (*red)[17]  = (float(*)[17])(arena + 9472);
        float* nrm = (float*)(arena + 13824);
        const int l0 = t0;
        const float* qb = Qb + (size_t)bh * 65536;

        float acc[4][4] = {};
        const float4* q4 = (const float4*)qb;
        for (int d0 = 0; d0 < 64; d0 += 16) {
            {
                int r = tid >> 2, c4 = tid & 3;
                float4 t = q4[(size_t)(l0 + r)*16 + (d0 >> 2) + c4];
                *(float4*)&qs[r][c4*4] = t;
            }
            {
                int r = tid >> 4, c4 = tid & 15;
                float4 t = ((const float4*)AF)[(size_t)bh*1024 + (size_t)(d0 + r)*16 + c4];
                *(float4*)&As16[r][c4*4] = t;
            }
            __syncthreads();
            float qreg[4][16];
            #pragma unroll
            for (int i = 0; i < 4; ++i)
                #pragma unroll
                for (int c = 0; c < 4; ++c) {
                    float4 t = *(const float4*)&qs[ty*4+i][c*4];
                    qreg[i][c*4+0] = t.x; qreg[i][c*4+1] = t.y;
                    qreg[i][c*4+2] = t.z; qreg[i][c*4+3] = t.w;
                }
            #pragma unroll
            for (int dd = 0; dd < 16; ++dd) {
                float4 b4 = *(const float4*)&As16[dd][tx*4];
                float bb[4] = {b4.x, b4.y, b4.z, b4.w};
                #pragma unroll
                for (int ii = 0; ii < 4; ++ii)
                    #pragma unroll
                    for (int jj = 0; jj < 4; ++jj)
                        acc[ii][jj] += qreg[ii][dd] * bb[jj];
            }
            __syncthreads();
        }
        #pragma unroll
        for (int i = 0; i < 4; ++i) {
            red[ty*4+i][tx] = acc[i][0]*acc[i][0] + acc[i][1]*acc[i][1]
                            + acc[i][2]*acc[i][2] + acc[i][3]*acc[i][3];
        }
        __syncthreads();
        if (tid < 64) {
            float s = 0.0f;
            #pragma unroll
            for (int t = 0; t < 16; ++t) s += red[tid][t];
            nrm[tid] = fmaxf(sqrtf(s), 1e-5f);
        }
        __syncthreads();
        const int b = bh >> 3, hd = bh & 7;
        #pragma unroll
        for (int i = 0; i < 4; ++i) {
            int lr = ty*4 + i;
            float inv = 1.0f / nrm[lr];
            ushort4 o;
            o.x = f2bf(acc[i][0]*inv); o.y = f2bf(acc[i][1]*inv);
            o.z = f2bf(acc[i][2]*inv); o.w = f2bf(acc[i][3]*inv);
            *(ushort4*)&UB[(size_t)(b*1024 + l0 + lr)*512 + hd*64 + tx*4] = o;
        }
    }
}

// ---------------------------------------------------------------------------
// K3: out = UB[2048][512](bf16) @ WOT^T + bo.  256 even 64x64 tiles.
// ---------------------------------------------------------------------------
__global__ __launch_bounds__(256) void k_out(
    const unsigned short* __restrict__ ub, const unsigned short* __restrict__ woT,
    const float* __restrict__ bo, float* __restrict__ out)
{
    const int tid = threadIdx.x;
    const int lane = tid & 63, wave = tid >> 6;
    const int qd = lane >> 4, ln = lane & 15;
    const int m0 = (blockIdx.x >> 3) * 64;
    const int n0 = (blockIdx.x & 7) * 64;

    __shared__ unsigned short As[64*72];
    __shared__ unsigned short Bs[64*72];

    floatx4 acc[4];
    #pragma unroll
    for (int i = 0; i < 4; ++i) acc[i] = (floatx4){0.f,0.f,0.f,0.f};

    const uint4* Ag = (const uint4*)ub;
    const uint4* Bg = (const uint4*)woT;
    for (int k0 = 0; k0 < 512; k0 += 64) {
        #pragma unroll
        for (int s = 0; s < 2; ++s) {
            int idx = s*256 + tid;
            int r = idx >> 3, cp = idx & 7;
            *(uint4*)&As[r*72 + cp*8] = Ag[(size_t)(m0 + r)*64 + (k0 >> 3) + cp];
            *(uint4*)&Bs[r*72 + cp*8] = Bg[(size_t)(n0 + r)*64 + (k0 >> 3) + cp];
        }
        __syncthreads();
        short8 af0 = *(const short8*)&As[(wave*16 + ln)*72 + qd*8];
        short8 af1 = *(const short8*)&As[(wave*16 + ln)*72 + 32 + qd*8];
        #pragma unroll
        for (int ni = 0; ni < 4; ++ni) {
            short8 bf0 = *(const short8*)&Bs[(ni*16 + ln)*72 + qd*8];
            short8 bf1 = *(const short8*)&Bs[(ni*16 + ln)*72 + 32 + qd*8];
            acc[ni] = __builtin_amdgcn_mfma_f32_16x16x32_bf16(af0, bf0, acc[ni], 0, 0, 0);
            acc[ni] = __builtin_amdgcn_mfma_f32_16x16x32_bf16(af1, bf1, acc[ni], 0, 0, 0);
        }
        __syncthreads();
    }

    #pragma unroll
    for (int ni = 0; ni < 4; ++ni) {
        int gcol = n0 + ni*16 + ln;
        float bb = bo[gcol];
        #pragma unroll
        for (int reg = 0; reg < 4; ++reg) {
            int row = m0 + wave*16 + qd*4 + reg;
            out[(size_t)row*512 + gcol] = acc[ni][reg] + bb;
        }
    }
}

extern "C" void kernel_launch(void* const* d_in, const int* in_sizes, int n_in,
                              void* d_out, int out_size, void* d_ws, size_t ws_size,
                              hipStream_t stream)
{
    const float* x   = (const float*)d_in[0];
    const float* sb  = (const float*)d_in[1];
    const float* wq  = (const float*)d_in[2];
    const float* bq  = (const float*)d_in[3];
    const float* wk  = (const float*)d_in[4];
    const float* bk  = (const float*)d_in[5];
    const float* wv  = (const float*)d_in[6];
    const float* bv  = (const float*)d_in[7];
    const float* wo  = (const float*)d_in[8];
    const float* bo  = (const float*)d_in[9];
    const float* wg  = (const float*)d_in[10];
    const float* wgb = (const float*)d_in[11];
    float* out = (float*)d_out;
    float* ws  = (float*)d_ws;

    // workspace layout (float offsets)
    unsigned int* CNT = (unsigned int*)ws;  // 1536 B (k1 slot 0; k2 slots 0,64)
    float* AF  = ws + 1024;                 // 65536 f32 (atomic-accumulated)
    float* GL  = AF + 65536;                // 16384
    float* Qb  = GL + 16384;                // 1048576
    float* fp  = Qb + 1048576;
    unsigned short* WT  = (unsigned short*)fp;              // 786432 u16
    unsigned short* WOT = WT  + 786432;                     // 262144
    unsigned short* UB  = WOT + 262144;                     // 1048576
    unsigned short* UB2 = UB  + 1048576;                    // 2097152

    hipMemsetAsync(CNT, 0, 1536, stream);     // barrier counters (k1+k2)
    hipMemsetAsync(AF, 0, 262144, stream);    // atomic accumulator
    k_qkvw<<<dim3(256), 256, 0, stream>>>(x, wq, wk, wv, wo, bq, bk, bv,
                                          WT, WOT, Qb, UB2, CNT);
    k_core<<<dim3(256), 256, 0, stream>>>(sb, wg, wgb, UB2, Qb,
                                          GL, AF, UB, CNT + 128);
    k_out <<<dim3(256), 256, 0, stream>>>(UB, WOT, bo, out);
}

// Round 8
// 162.215 us; speedup vs baseline: 1.1090x; 1.1090x over previous
//
#include <hip/hip_runtime.h>
#include <math.h>

// Problem constants: B=2, L=1024, D=512, H=8, h=64, K=H=8, EPS=1e-5
// R8: revert to split kernels (the R1 structure, 143.7us verified) after the
// grid-barrier arc (R3-R7) proved in-kernel barriers cost 15-25us each vs
// ~5us per launch boundary.  Changes vs R1:
//  - k_prep deleted: qkv casts A inline from fp32 x (R7-verified), self-packs
//    its B weight tile per k-chunk (register transpose, bit-identical Bs),
//    and packs WOT (64 units across blocks 0-63) for k_out; conv_gate casts
//    wg inline (R7-verified).
//  - k_qkv re-tiled to 256x64 tiles, grid (24,8): uniform 1 tile/block.
//  - k_out: 256 even 64x64 tiles (R6-P5-verified).
//  - conv_gate / amat / ctxt: R1 verbatim.
// 5 launches, 4 boundaries, no barriers/atomics/memsets.

typedef __attribute__((ext_vector_type(8))) short short8;
typedef __attribute__((ext_vector_type(4))) float floatx4;

__device__ __forceinline__ unsigned short f2bf(float f) {
    unsigned int u = __float_as_uint(f);
    unsigned int r = (u + 0x7FFFu + ((u >> 16) & 1u)) >> 16;   // RNE
    return (unsigned short)r;
}

// ---------------------------------------------------------------------------
// K1: QKV projection, 256x64 tiles, grid (24 nt, 8 mg), 256 thr.
// A: inline bf16 cast from fp32 x.  B: per-chunk register-transpose self-pack
// from fp32 weights (identical values/layout to the old WT path).
// Blocks flat<64 also transpose-pack WOT for k_out.
// ---------------------------------------------------------------------------
__global__ __launch_bounds__(256) void k_qkv(
    const float* __restrict__ x,
    const float* __restrict__ wq, const float* __restrict__ wk,
    const float* __restrict__ wv, const float* __restrict__ wo,
    const float* __restrict__ bq, const float* __restrict__ bk,
    const float* __restrict__ bv,
    unsigned short* __restrict__ WOT,
    float* __restrict__ Qb, unsigned short* __restrict__ UB2)
{
    const int tid = threadIdx.x;
    const int lane = tid & 63, wave = tid >> 6;
    const int qd = lane >> 4, ln = lane & 15;
    const int nt = blockIdx.x, mg = blockIdx.y;
    const int n0 = nt * 64;
    const int z = n0 >> 9, c0 = n0 & 511;
    const float* wsrc = (z == 0) ? wq : (z == 1) ? wk : wv;

    __shared__ __align__(16) unsigned char arena[46080];
    unsigned short* As = (unsigned short*)arena;            // 256*72 u16
    unsigned short* Bs = (unsigned short*)(arena + 36864);  // 64*72 u16

    // ---- one-time WOT pack (64 units over blocks flat<64) ----
    const int flat = mg * 24 + nt;
    if (flat < 64) {
        float (*sf)[65] = (float(*)[65])arena;   // 16640 B (overlaps As; pre-loop)
        const int nt2 = flat >> 3, kt = flat & 7;
        const int n0p = nt2 * 64, k0p = kt * 64;
        const int rr = tid >> 4, c4 = tid & 15;
        #pragma unroll
        for (int g = 0; g < 4; ++g) {
            int r = g*16 + rr;
            float4 v = *(const float4*)&wo[(size_t)(k0p + r)*512 + n0p + c4*4];
            sf[r][c4*4+0]=v.x; sf[r][c4*4+1]=v.y; sf[r][c4*4+2]=v.z; sf[r][c4*4+3]=v.w;
        }
        __syncthreads();
        #pragma unroll
        for (int g = 0; g < 4; ++g) {
            int c = g*16 + rr;
            int kk = c4*4;
            ushort4 o;
            o.x = f2bf(sf[kk+0][c]); o.y = f2bf(sf[kk+1][c]);
            o.z = f2bf(sf[kk+2][c]); o.w = f2bf(sf[kk+3][c]);
            *(ushort4*)&WOT[(size_t)(n0p + c)*512 + k0p + kk] = o;
        }
    }
    __syncthreads();

    const int m0 = mg * 256;
    const int wm = wave * 64;

    floatx4 acc[4][4];
    #pragma unroll
    for (int i = 0; i < 4; ++i)
        #pragma unroll
        for (int j = 0; j < 4; ++j)
            acc[i][j] = (floatx4){0.f, 0.f, 0.f, 0.f};

    for (int k0 = 0; k0 < 512; k0 += 64) {
        // ---- A stage: inline cast x -> bf16 (256 rows x 64 k) ----
        #pragma unroll
        for (int s = 0; s < 8; ++s) {
            int idx = s*256 + tid;
            int r = idx >> 3, cp = idx & 7;
            const float* xs = &x[(size_t)(m0 + r)*512 + k0 + cp*8];
            float4 a = *(const float4*)xs;
            float4 b = *(const float4*)(xs + 4);
            uint4 o;
            o.x = f2bf(a.x) | ((unsigned)f2bf(a.y) << 16);
            o.y = f2bf(a.z) | ((unsigned)f2bf(a.w) << 16);
            o.z = f2bf(b.x) | ((unsigned)f2bf(b.y) << 16);
            o.w = f2bf(b.z) | ((unsigned)f2bf(b.w) << 16);
            *(uint4*)&As[r*72 + cp*8] = o;
        }
        // ---- B stage: register-transpose self-pack ----
        // Bs[n][k] = f2bf(w_z[k0+k][c0+n]) -- identical to the old WT path.
        {
            float v[16];
            #pragma unroll
            for (int j = 0; j < 16; ++j)
                v[j] = wsrc[(size_t)(k0 + wave*16 + j)*512 + c0 + lane];
            uint4 o1, o2;
            o1.x = f2bf(v[0])  | ((unsigned)f2bf(v[1])  << 16);
            o1.y = f2bf(v[2])  | ((unsigned)f2bf(v[3])  << 16);
            o1.z = f2bf(v[4])  | ((unsigned)f2bf(v[5])  << 16);
            o1.w = f2bf(v[6])  | ((unsigned)f2bf(v[7])  << 16);
            o2.x = f2bf(v[8])  | ((unsigned)f2bf(v[9])  << 16);
            o2.y = f2bf(v[10]) | ((unsigned)f2bf(v[11]) << 16);
            o2.z = f2bf(v[12]) | ((unsigned)f2bf(v[13]) << 16);
            o2.w = f2bf(v[14]) | ((unsigned)f2bf(v[15]) << 16);
            *(uint4*)&Bs[lane*72 + wave*16]     = o1;
            *(uint4*)&Bs[lane*72 + wave*16 + 8] = o2;
        }
        __syncthreads();
        short8 af0[4], af1[4], bf0[4], bf1[4];
        #pragma unroll
        for (int mi = 0; mi < 4; ++mi) {
            af0[mi] = *(const short8*)&As[(wm + mi*16 + ln)*72 + qd*8];
            af1[mi] = *(const short8*)&As[(wm + mi*16 + ln)*72 + 32 + qd*8];
        }
        #pragma unroll
        for (int ni = 0; ni < 4; ++ni) {
            bf0[ni] = *(const short8*)&Bs[(ni*16 + ln)*72 + qd*8];
            bf1[ni] = *(const short8*)&Bs[(ni*16 + ln)*72 + 32 + qd*8];
        }
        #pragma unroll
        for (int mi = 0; mi < 4; ++mi)
            #pragma unroll
            for (int ni = 0; ni < 4; ++ni) {
                acc[mi][ni] = __builtin_amdgcn_mfma_f32_16x16x32_bf16(
                    af0[mi], bf0[ni], acc[mi][ni], 0, 0, 0);
                acc[mi][ni] = __builtin_amdgcn_mfma_f32_16x16x32_bf16(
                    af1[mi], bf1[ni], acc[mi][ni], 0, 0, 0);
            }
        __syncthreads();
    }

    if (z == 0) {
        #pragma unroll
        for (int mi = 0; mi < 4; ++mi) {
            #pragma unroll
            for (int ni = 0; ni < 4; ++ni) {
                int c = (n0 + ni*16 + ln) & 511;
                int head = c >> 6, dd = c & 63;
                float bb = bq[c];
                #pragma unroll
                for (int reg = 0; reg < 4; ++reg) {
                    int row = m0 + wm + mi*16 + qd*4 + reg;
                    int b = row >> 10, l = row & 1023;
                    Qb[(size_t)((b*8 + head)*1024 + l)*64 + dd] =
                        acc[mi][ni][reg] + bb;
                }
            }
        }
    } else {
        const float scale = (z == 1) ? 0.125f : 1.0f;
        const float* bias = (z == 1) ? bk : bv;
        unsigned short* dst = UB2 + (size_t)(z-1) * 16 * 64 * 1024;
        #pragma unroll
        for (int mi = 0; mi < 4; ++mi) {
            #pragma unroll
            for (int ni = 0; ni < 4; ++ni) {
                int c = (n0 + ni*16 + ln) & 511;
                int head = c >> 6, dd = c & 63;
                float bb = bias[c];
                int row0 = m0 + wm + mi*16 + qd*4;
                int b = row0 >> 10, l0 = row0 & 1023;
                ushort4 o;
                o.x = f2bf((acc[mi][ni][0] + bb) * scale);
                o.y = f2bf((acc[mi][ni][1] + bb) * scale);
                o.z = f2bf((acc[mi][ni][2] + bb) * scale);
                o.w = f2bf((acc[mi][ni][3] + bb) * scale);
                *(ushort4*)&dst[((size_t)((b*8 + head)*64) + dd)*1024 + l0] = o;
            }
        }
    }
}

// ---------------------------------------------------------------------------
// K2: conv (BOTH tensors) + gate, fused (R1 verbatim; wg cast inline).
// grid (16 bh, 16 it), 256 thr.
// ---------------------------------------------------------------------------
__global__ __launch_bounds__(256) void k_conv_gate(
    const float* __restrict__ sb,
    const unsigned short* __restrict__ ub2,
    const float* __restrict__ wgw, const float* __restrict__ wg_b,
    float* __restrict__ kc, float* __restrict__ vc,
    float* __restrict__ gl)
{
    const int tid = threadIdx.x;
    const int lane = tid & 63, wave = tid >> 6;
    const int q = lane >> 4, ln = lane & 15;
    const int bh  = blockIdx.x, h = bh & 7;
    const int it  = blockIdx.y;
    const int t0  = it * 64;

    __shared__ unsigned short revf[1152];  // revf[i] = filt(1087-i), 0-padded
    __shared__ unsigned short Bk[64*72];   // k-conv B tile; later KCb (bf16)
    __shared__ unsigned short Bv[64*72];   // v-conv B tile; later Wgb

    for (int i = tid; i < 1152; i += 256) {
        int d = 1087 - i;
        revf[i] = (d >= 0 && d < 1024) ? f2bf(sb[d*8 + h]) : (unsigned short)0;
    }

    const uint4* Bg = (const uint4*)ub2;
    const size_t bk_base = (size_t)bh * 8192;          // tensor 0 (k)
    const size_t bv_base = (size_t)(16 + bh) * 8192;   // tensor 1 (v)

    floatx4 acck[4], accv[4];
    #pragma unroll
    for (int i = 0; i < 4; ++i) {
        acck[i] = (floatx4){0.f,0.f,0.f,0.f};
        accv[i] = (floatx4){0.f,0.f,0.f,0.f};
    }

    const int kend = t0 + 64;
    const int arow = 1087 - t0 - (wave*16 + ln);   // + k0 + q*8 -> frag base
    for (int k0 = 0; k0 < kend; k0 += 64) {
        #pragma unroll
        for (int s = 0; s < 2; ++s) {
            int idx = s*256 + tid;
            int r = idx >> 3, cp = idx & 7;
            *(uint4*)&Bk[r*72 + cp*8] = Bg[bk_base + (size_t)r*128 + (k0 >> 3) + cp];
            *(uint4*)&Bv[r*72 + cp*8] = Bg[bv_base + (size_t)r*128 + (k0 >> 3) + cp];
        }
        __syncthreads();                   // also covers revf on first iter
        const int ab = arow + k0 + q*8;
        short8 a0, a1;
        #pragma unroll
        for (int j = 0; j < 8; ++j) {
            a0[j] = (short)revf[ab + j];
            a1[j] = (short)revf[ab + 32 + j];
        }
        #pragma unroll
        for (int ni = 0; ni < 4; ++ni) {
            short8 kb0 = *(const short8*)&Bk[(ni*16 + ln)*72 + q*8];
            short8 kb1 = *(const short8*)&Bk[(ni*16 + ln)*72 + 32 + q*8];
            short8 vb0 = *(const short8*)&Bv[(ni*16 + ln)*72 + q*8];
            short8 vb1 = *(const short8*)&Bv[(ni*16 + ln)*72 + 32 + q*8];
            acck[ni] = __builtin_amdgcn_mfma_f32_16x16x32_bf16(a0, kb0, acck[ni], 0, 0, 0);
            acck[ni] = __builtin_amdgcn_mfma_f32_16x16x32_bf16(a1, kb1, acck[ni], 0, 0, 0);
            accv[ni] = __builtin_amdgcn_mfma_f32_16x16x32_bf16(a0, vb0, accv[ni], 0, 0, 0);
            accv[ni] = __builtin_amdgcn_mfma_f32_16x16x32_bf16(a1, vb1, accv[ni], 0, 0, 0);
        }
        __syncthreads();
    }

    // ---- epilogue: write conv outputs, stage KCb (bf16) + Wgb into LDS ----
    float* kdst = kc + (size_t)bh * 65536;
    float* vdst = vc + (size_t)bh * 65536;
    #pragma unroll
    for (int ni = 0; ni < 4; ++ni)
        #pragma unroll
        for (int reg = 0; reg < 4; ++reg) {
            int row = wave*16 + q*4 + reg;           // local row in tile
            int grow = t0 + row;
            kdst[(size_t)grow*64 + ni*16 + ln] = acck[ni][reg];
            vdst[(size_t)grow*64 + ni*16 + ln] = accv[ni][reg];
            Bk[row*72 + ni*16 + ln] = f2bf(acck[ni][reg]);
        }
    #pragma unroll
    for (int s = 0; s < 2; ++s) {          // Wgb inline cast from wg fp32
        int idx = s*256 + tid;
        int r = idx >> 3, cp = idx & 7;
        const float* ws2 = &wgw[r*64 + cp*8];
        float4 a = *(const float4*)ws2;
        float4 b = *(const float4*)(ws2 + 4);
        uint4 o;
        o.x = f2bf(a.x) | ((unsigned)f2bf(a.y) << 16);
        o.y = f2bf(a.z) | ((unsigned)f2bf(a.w) << 16);
        o.z = f2bf(b.x) | ((unsigned)f2bf(b.y) << 16);
        o.w = f2bf(b.z) | ((unsigned)f2bf(b.w) << 16);
        *(uint4*)&Bv[r*72 + cp*8] = o;
    }
    __syncthreads();

    // ---- gate MFMA: T = KCb @ Wgb^T  (K=64, two 32-chunks) ----
    floatx4 T[4];
    #pragma unroll
    for (int mt = 0; mt < 4; ++mt) T[mt] = (floatx4){0.f,0.f,0.f,0.f};
    #pragma unroll
    for (int k0g = 0; k0g < 64; k0g += 32) {
        short8 a = *(const short8*)&Bk[(wave*16 + ln)*72 + k0g + q*8];
        #pragma unroll
        for (int mt = 0; mt < 4; ++mt) {
            short8 b = *(const short8*)&Bv[(mt*16 + ln)*72 + k0g + q*8];
            T[mt] = __builtin_amdgcn_mfma_f32_16x16x32_bf16(a, b, T[mt], 0, 0, 0);
        }
    }

    // rowsum of V .* T — V comes straight from the accv registers
    float part[4] = {0.f, 0.f, 0.f, 0.f};
    #pragma unroll
    for (int mt = 0; mt < 4; ++mt)
        #pragma unroll
        for (int reg = 0; reg < 4; ++reg)
            part[reg] += T[mt][reg] * accv[mt][reg];
    #pragma unroll
    for (int reg = 0; reg < 4; ++reg) {
        part[reg] += __shfl_xor(part[reg], 1);
        part[reg] += __shfl_xor(part[reg], 2);
        part[reg] += __shfl_xor(part[reg], 4);
        part[reg] += __shfl_xor(part[reg], 8);
    }
    if (ln == 0) {
        const float wgbias = wg_b[0];
        #pragma unroll
        for (int reg = 0; reg < 4; ++reg) {
            int l = t0 + wave*16 + q*4 + reg;
            float s = part[reg] + wgbias;
            float rr = fmaxf(s, 0.0f);
            gl[bh*1024 + l] = rr*rr + 1e-5f;
        }
    }
}

// ---------------------------------------------------------------------------
// K3: A_part[slc][bh] (R1 verbatim).  grid (16 bh, 16 slices of 64), 256 thr.
// ---------------------------------------------------------------------------
__global__ __launch_bounds__(256) void k_amat(
    const float* __restrict__ kc, const float* __restrict__ vc,
    const float* __restrict__ gl, float* __restrict__ apart)
{
    const int tid = threadIdx.x, tx = tid & 15, ty = tid >> 4;
    const int lane = tid & 63, wave = tid >> 6;
    const int bh = blockIdx.x, slc = blockIdx.y;
    const float* kb = kc + (size_t)bh * 65536;
    const float* vb = vc + (size_t)bh * 65536;

    __shared__ float scanA[4], scanB[4];
    __shared__ float wfull[1024];
    __shared__ __align__(16) float vs[16][68];
    __shared__ __align__(16) float ks2[16][68];

    {
        const float4 g4 = ((const float4*)(gl + bh*1024))[tid];
        float g[4] = {g4.x, g4.y, g4.z, g4.w};
        float p[4];
        p[0]=g[0]; p[1]=p[0]+g[1]; p[2]=p[1]+g[2]; p[3]=p[2]+g[3];
        float x = p[3];
        #pragma unroll
        for (int off = 1; off < 64; off <<= 1) {
            float t = __shfl_up(x, off);
            if (lane >= off) x += t;
        }
        if (lane == 63) scanA[wave] = x;
        __syncthreads();
        float wb = 0.f;
        #pragma unroll
        for (int wv = 0; wv < 4; ++wv) wb += (wv < wave) ? scanA[wv] : 0.f;
        const float base = wb + x - p[3];
        float r[4], pr[4];
        #pragma unroll
        for (int u = 0; u < 4; ++u) r[u] = 1.0f / (base + p[u] + 1e-5f);
        pr[0]=r[0]; pr[1]=pr[0]+r[1]; pr[2]=pr[1]+r[2]; pr[3]=pr[2]+r[3];
        float y = pr[3];
        #pragma unroll
        for (int off = 1; off < 64; off <<= 1) {
            float t = __shfl_up(y, off);
            if (lane >= off) y += t;
        }
        if (lane == 63) scanB[wave] = y;
        __syncthreads();
        float rb = 0.f, Rtot = 0.f;
        #pragma unroll
        for (int wv = 0; wv < 4; ++wv) {
            rb   += (wv < wave) ? scanB[wv] : 0.f;
            Rtot += scanB[wv];
        }
        const float baser = rb + y - pr[3];
        wfull[tid*4+0] = g[0] * (Rtot - (baser + pr[0]) + r[0]);
        wfull[tid*4+1] = g[1] * (Rtot - (baser + pr[1]) + r[1]);
        wfull[tid*4+2] = g[2] * (Rtot - (baser + pr[2]) + r[2]);
        wfull[tid*4+3] = g[3] * (Rtot - (baser + pr[3]) + r[3]);
    }
    __syncthreads();

    float acc[4][4] = {};
    const float4* k4 = (const float4*)kb;
    const float4* v4 = (const float4*)vb;
    for (int j0 = slc*64; j0 < slc*64 + 64; j0 += 16) {
        {
            int r = tid >> 4, c4 = tid & 15;
            *(float4*)&vs[r][c4*4]  = v4[(size_t)(j0 + r)*16 + c4];
            *(float4*)&ks2[r][c4*4] = k4[(size_t)(j0 + r)*16 + c4];
        }
        __syncthreads();
        #pragma unroll
        for (int jj = 0; jj < 16; ++jj) {
            float wj = wfull[j0 + jj];
            float a[4];
            a[0] = vs[jj][ty*4+0]*wj; a[1] = vs[jj][ty*4+1]*wj;
            a[2] = vs[jj][ty*4+2]*wj; a[3] = vs[jj][ty*4+3]*wj;
            float4 b4 = *(const float4*)&ks2[jj][tx*4];
            float bb[4] = {b4.x, b4.y, b4.z, b4.w};
            #pragma unroll
            for (int ii = 0; ii < 4; ++ii)
                #pragma unroll
                for (int jc = 0; jc < 4; ++jc)
                    acc[ii][jc] += a[ii] * bb[jc];
        }
        __syncthreads();
    }
    float* ap = apart + (size_t)(slc*16 + bh) * 4096;
    #pragma unroll
    for (int i = 0; i < 4; ++i) {
        float4 o = { acc[i][0], acc[i][1], acc[i][2], acc[i][3] };
        *(float4*)&ap[(ty*4+i)*64 + tx*4] = o;
    }
}

// ---------------------------------------------------------------------------
// K4: ctxt = q @ A (summing 16 A-partials on load), row-normalize, bf16 -> UB.
// (R1 verbatim.)  grid (16, 16), 256 thr.
// ---------------------------------------------------------------------------
__global__ __launch_bounds__(256) void k_ctxt(
    const float* __restrict__ q, const float* __restrict__ apart,
    unsigned short* __restrict__ ub)
{
    const int tid = threadIdx.x, tx = tid & 15, ty = tid >> 4;
    const int l0 = blockIdx.x * 64;
    const int bh = blockIdx.y;
    const float* qb = q + (size_t)bh * 65536;

    __shared__ __align__(16) float qs[64][20];
    __shared__ __align__(16) float As[16][68];
    float acc[4][4] = {};
    const float4* q4 = (const float4*)qb;
    const float4* a4 = (const float4*)apart;
    for (int d0 = 0; d0 < 64; d0 += 16) {
        {
            int r = tid >> 2, c4 = tid & 3;
            float4 t = q4[(size_t)(l0 + r)*16 + (d0 >> 2) + c4];
            *(float4*)&qs[r][c4*4] = t;
        }
        {
            int r = tid >> 4, c4 = tid & 15;
            size_t o = (size_t)(d0 + r)*16 + c4;
            float4 t = a4[(size_t)(0*16 + bh)*1024 + o];
            #pragma unroll
            for (int s = 1; s < 16; ++s) {
                float4 u = a4[(size_t)(s*16 + bh)*1024 + o];
                t.x += u.x; t.y += u.y; t.z += u.z; t.w += u.w;
            }
            *(float4*)&As[r][c4*4] = t;
        }
        __syncthreads();
        float qreg[4][16];
        #pragma unroll
        for (int i = 0; i < 4; ++i)
            #pragma unroll
            for (int c = 0; c < 4; ++c) {
                float4 t = *(const float4*)&qs[ty*4+i][c*4];
                qreg[i][c*4+0] = t.x; qreg[i][c*4+1] = t.y;
                qreg[i][c*4+2] = t.z; qreg[i][c*4+3] = t.w;
            }
        #pragma unroll
        for (int dd = 0; dd < 16; ++dd) {
            float4 b4 = *(const float4*)&As[dd][tx*4];
            float bb[4] = {b4.x, b4.y, b4.z, b4.w};
            #pragma unroll
            for (int ii = 0; ii < 4; ++ii)
                #pragma unroll
                for (int jj = 0; jj < 4; ++jj)
                    acc[ii][jj] += qreg[ii][dd] * bb[jj];
        }
        __syncthreads();
    }
    __shared__ float red[64][17];
    __shared__ float nrm[64];
    #pragma unroll
    for (int i = 0; i < 4; ++i) {
        red[ty*4+i][tx] = acc[i][0]*acc[i][0] + acc[i][1]*acc[i][1]
                        + acc[i][2]*acc[i][2] + acc[i][3]*acc[i][3];
    }
    __syncthreads();
    if (tid < 64) {
        float s = 0.0f;
        #pragma unroll
        for (int t = 0; t < 16; ++t) s += red[tid][t];
        nrm[tid] = fmaxf(sqrtf(s), 1e-5f);
    }
    __syncthreads();
    const int b = bh >> 3, hd = bh & 7;
    #pragma unroll
    for (int i = 0; i < 4; ++i) {
        int lr = ty*4 + i;
        float inv = 1.0f / nrm[lr];
        ushort4 o;
        o.x = f2bf(acc[i][0]*inv); o.y = f2bf(acc[i][1]*inv);
        o.z = f2bf(acc[i][2]*inv); o.w = f2bf(acc[i][3]*inv);
        *(ushort4*)&ub[(size_t)(b*1024 + l0 + lr)*512 + hd*64 + tx*4] = o;
    }
}

// ---------------------------------------------------------------------------
// K5: out = UB[2048][512](bf16) @ WOT^T + bo.  256 even 64x64 tiles.
// ---------------------------------------------------------------------------
__global__ __launch_bounds__(256) void k_out(
    const unsigned short* __restrict__ ub, const unsigned short* __restrict__ woT,
    const float* __restrict__ bo, float* __restrict__ out)
{
    const int tid = threadIdx.x;
    const int lane = tid & 63, wave = tid >> 6;
    const int qd = lane >> 4, ln = lane & 15;
    const int m0 = (blockIdx.x >> 3) * 64;
    const int n0 = (blockIdx.x & 7) * 64;

    __shared__ unsigned short As[64*72];
    __shared__ unsigned short Bs[64*72];

    floatx4 acc[4];
    #pragma unroll
    for (int i = 0; i < 4; ++i) acc[i] = (floatx4){0.f,0.f,0.f,0.f};

    const uint4* Ag = (const uint4*)ub;
    const uint4* Bg = (const uint4*)woT;
    for (int k0 = 0; k0 < 512; k0 += 64) {
        #pragma unroll
        for (int s = 0; s < 2; ++s) {
            int idx = s*256 + tid;
            int r = idx >> 3, cp = idx & 7;
            *(uint4*)&As[r*72 + cp*8] = Ag[(size_t)(m0 + r)*64 + (k0 >> 3) + cp];
            *(uint4*)&Bs[r*72 + cp*8] = Bg[(size_t)(n0 + r)*64 + (k0 >> 3) + cp];
        }
        __syncthreads();
        short8 af0 = *(const short8*)&As[(wave*16 + ln)*72 + qd*8];
        short8 af1 = *(const short8*)&As[(wave*16 + ln)*72 + 32 + qd*8];
        #pragma unroll
        for (int ni = 0; ni < 4; ++ni) {
            short8 bf0 = *(const short8*)&Bs[(ni*16 + ln)*72 + qd*8];
            short8 bf1 = *(const short8*)&Bs[(ni*16 + ln)*72 + 32 + qd*8];
            acc[ni] = __builtin_amdgcn_mfma_f32_16x16x32_bf16(af0, bf0, acc[ni], 0, 0, 0);
            acc[ni] = __builtin_amdgcn_mfma_f32_16x16x32_bf16(af1, bf1, acc[ni], 0, 0, 0);
        }
        __syncthreads();
    }

    #pragma unroll
    for (int ni = 0; ni < 4; ++ni) {
        int gcol = n0 + ni*16 + ln;
        float bb = bo[gcol];
        #pragma unroll
        for (int reg = 0; reg < 4; ++reg) {
            int row = m0 + wave*16 + qd*4 + reg;
            out[(size_t)row*512 + gcol] = acc[ni][reg] + bb;
        }
    }
}

extern "C" void kernel_launch(void* const* d_in, const int* in_sizes, int n_in,
                              void* d_out, int out_size, void* d_ws, size_t ws_size,
                              hipStream_t stream)
{
    const float* x   = (const float*)d_in[0];
    const float* sb  = (const float*)d_in[1];
    const float* wq  = (const float*)d_in[2];
    const float* bq  = (const float*)d_in[3];
    const float* wk  = (const float*)d_in[4];
    const float* bk  = (const float*)d_in[5];
    const float* wv  = (const float*)d_in[6];
    const float* bv  = (const float*)d_in[7];
    const float* wo  = (const float*)d_in[8];
    const float* bo  = (const float*)d_in[9];
    const float* wg  = (const float*)d_in[10];
    const float* wgb = (const float*)d_in[11];
    float* out = (float*)d_out;
    float* ws  = (float*)d_ws;

    // workspace layout (float offsets)
    float* Qb  = ws;                        // 1048576 f32
    float* KC  = Qb + 1048576;              // 1048576
    float* VC  = KC + 1048576;              // 1048576
    float* GL  = VC + 1048576;              // 16384
    float* AP  = GL + 16384;                // 1048576
    float* fp  = AP + 1048576;
    unsigned short* WOT = (unsigned short*)fp;              // 262144 u16
    unsigned short* UB  = WOT + 262144;                     // 1048576
    unsigned short* UB2 = UB  + 1048576;                    // 2097152

    k_qkv      <<<dim3(24, 8),  256, 0, stream>>>(x, wq, wk, wv, wo,
                                                  bq, bk, bv, WOT, Qb, UB2);
    k_conv_gate<<<dim3(16, 16), 256, 0, stream>>>(sb, UB2, wg, wgb, KC, VC, GL);
    k_amat     <<<dim3(16, 16), 256, 0, stream>>>(KC, VC, GL, AP);
    k_ctxt     <<<dim3(16, 16), 256, 0, stream>>>(Qb, AP, UB);
    k_out      <<<dim3(256),    256, 0, stream>>>(UB, WOT, bo, out);
}

// Round 9
// 156.651 us; speedup vs baseline: 1.1484x; 1.0355x over previous
//
#include <hip/hip_runtime.h>
#include <math.h>

// Problem constants: B=2, L=1024, D=512, H=8, h=64, K=H=8, EPS=1e-5
// R9: R8 with the qkv occupancy regression fixed.  R8's 256x64 qkv tiles gave
// 192 blocks on 256 CUs (1 wave/SIMD -> no latency hiding for the strided
// fp32 B-pack loads).  Restore R1's 128x64 geometry, grid (24,16)=384 blocks
// (1.5 blocks/CU, 27.6KB LDS), keeping R8's verified prep-deletion: inline A
// cast from fp32 x, per-chunk B self-pack (bit-identical to the old WT path,
// absmax-verified in R8), WOT packed by blocks flat<64, wg cast inline in
// conv_gate.  conv_gate/amat/ctxt/out: R8 verbatim (R1-verified).
// 5 launches, 4 boundaries, no barriers/atomics/memsets.

typedef __attribute__((ext_vector_type(8))) short short8;
typedef __attribute__((ext_vector_type(4))) float floatx4;

__device__ __forceinline__ unsigned short f2bf(float f) {
    unsigned int u = __float_as_uint(f);
    unsigned int r = (u + 0x7FFFu + ((u >> 16) & 1u)) >> 16;   // RNE
    return (unsigned short)r;
}

// ---------------------------------------------------------------------------
// K1: QKV projection, 128x64 tiles, grid (24 nt, 16 mg), 256 thr.
// A: inline bf16 cast from fp32 x.  B: per-chunk register-transpose self-pack
// from fp32 weights (identical values/layout to the old WT path).
// Blocks flat<64 also transpose-pack WOT for k_out.
// ---------------------------------------------------------------------------
__global__ __launch_bounds__(256) void k_qkv(
    const float* __restrict__ x,
    const float* __restrict__ wq, const float* __restrict__ wk,
    const float* __restrict__ wv, const float* __restrict__ wo,
    const float* __restrict__ bq, const float* __restrict__ bk,
    const float* __restrict__ bv,
    unsigned short* __restrict__ WOT,
    float* __restrict__ Qb, unsigned short* __restrict__ UB2)
{
    const int tid = threadIdx.x;
    const int lane = tid & 63, wave = tid >> 6;
    const int qd = lane >> 4, ln = lane & 15;
    const int nt = blockIdx.x, mg = blockIdx.y;
    const int n0 = nt * 64;
    const int z = n0 >> 9, c0 = n0 & 511;
    const float* wsrc = (z == 0) ? wq : (z == 1) ? wk : wv;

    __shared__ __align__(16) unsigned char arena[27648];
    unsigned short* As = (unsigned short*)arena;            // 128*72 u16
    unsigned short* Bs = (unsigned short*)(arena + 18432);  // 64*72 u16

    // ---- one-time WOT pack (64 units over blocks flat<64) ----
    const int flat = mg * 24 + nt;
    if (flat < 64) {
        float (*sf)[65] = (float(*)[65])arena;   // 16640 B (overlaps As; pre-loop)
        const int nt2 = flat >> 3, kt = flat & 7;
        const int n0p = nt2 * 64, k0p = kt * 64;
        const int rr = tid >> 4, c4 = tid & 15;
        #pragma unroll
        for (int g = 0; g < 4; ++g) {
            int r = g*16 + rr;
            float4 v = *(const float4*)&wo[(size_t)(k0p + r)*512 + n0p + c4*4];
            sf[r][c4*4+0]=v.x; sf[r][c4*4+1]=v.y; sf[r][c4*4+2]=v.z; sf[r][c4*4+3]=v.w;
        }
        __syncthreads();
        #pragma unroll
        for (int g = 0; g < 4; ++g) {
            int c = g*16 + rr;
            int kk = c4*4;
            ushort4 o;
            o.x = f2bf(sf[kk+0][c]); o.y = f2bf(sf[kk+1][c]);
            o.z = f2bf(sf[kk+2][c]); o.w = f2bf(sf[kk+3][c]);
            *(ushort4*)&WOT[(size_t)(n0p + c)*512 + k0p + kk] = o;
        }
    }
    __syncthreads();

    const int m0 = mg * 128;
    const int wm = wave * 32;

    floatx4 acc[2][4];
    #pragma unroll
    for (int i = 0; i < 2; ++i)
        #pragma unroll
        for (int j = 0; j < 4; ++j)
            acc[i][j] = (floatx4){0.f, 0.f, 0.f, 0.f};

    for (int k0 = 0; k0 < 512; k0 += 64) {
        // ---- A stage: inline cast x -> bf16 (128 rows x 64 k) ----
        #pragma unroll
        for (int s = 0; s < 4; ++s) {
            int idx = s*256 + tid;
            int r = idx >> 3, cp = idx & 7;
            const float* xs = &x[(size_t)(m0 + r)*512 + k0 + cp*8];
            float4 a = *(const float4*)xs;
            float4 b = *(const float4*)(xs + 4);
            uint4 o;
            o.x = f2bf(a.x) | ((unsigned)f2bf(a.y) << 16);
            o.y = f2bf(a.z) | ((unsigned)f2bf(a.w) << 16);
            o.z = f2bf(b.x) | ((unsigned)f2bf(b.y) << 16);
            o.w = f2bf(b.z) | ((unsigned)f2bf(b.w) << 16);
            *(uint4*)&As[r*72 + cp*8] = o;
        }
        // ---- B stage: register-transpose self-pack ----
        // Bs[n][k] = f2bf(w_z[k0+k][c0+n]) -- identical to the old WT path.
        {
            float v[16];
            #pragma unroll
            for (int j = 0; j < 16; ++j)
                v[j] = wsrc[(size_t)(k0 + wave*16 + j)*512 + c0 + lane];
            uint4 o1, o2;
            o1.x = f2bf(v[0])  | ((unsigned)f2bf(v[1])  << 16);
            o1.y = f2bf(v[2])  | ((unsigned)f2bf(v[3])  << 16);
            o1.z = f2bf(v[4])  | ((unsigned)f2bf(v[5])  << 16);
            o1.w = f2bf(v[6])  | ((unsigned)f2bf(v[7])  << 16);
            o2.x = f2bf(v[8])  | ((unsigned)f2bf(v[9])  << 16);
            o2.y = f2bf(v[10]) | ((unsigned)f2bf(v[11]) << 16);
            o2.z = f2bf(v[12]) | ((unsigned)f2bf(v[13]) << 16);
            o2.w = f2bf(v[14]) | ((unsigned)f2bf(v[15]) << 16);
            *(uint4*)&Bs[lane*72 + wave*16]     = o1;
            *(uint4*)&Bs[lane*72 + wave*16 + 8] = o2;
        }
        __syncthreads();
        short8 af0[2], af1[2], bf0[4], bf1[4];
        #pragma unroll
        for (int mi = 0; mi < 2; ++mi) {
            af0[mi] = *(const short8*)&As[(wm + mi*16 + ln)*72 + qd*8];
            af1[mi] = *(const short8*)&As[(wm + mi*16 + ln)*72 + 32 + qd*8];
        }
        #pragma unroll
        for (int ni = 0; ni < 4; ++ni) {
            bf0[ni] = *(const short8*)&Bs[(ni*16 + ln)*72 + qd*8];
            bf1[ni] = *(const short8*)&Bs[(ni*16 + ln)*72 + 32 + qd*8];
        }
        #pragma unroll
        for (int mi = 0; mi < 2; ++mi)
            #pragma unroll
            for (int ni = 0; ni < 4; ++ni) {
                acc[mi][ni] = __builtin_amdgcn_mfma_f32_16x16x32_bf16(
                    af0[mi], bf0[ni], acc[mi][ni], 0, 0, 0);
                acc[mi][ni] = __builtin_amdgcn_mfma_f32_16x16x32_bf16(
                    af1[mi], bf1[ni], acc[mi][ni], 0, 0, 0);
            }
        __syncthreads();
    }

    if (z == 0) {
        #pragma unroll
        for (int mi = 0; mi < 2; ++mi) {
            #pragma unroll
            for (int ni = 0; ni < 4; ++ni) {
                int c = (n0 + ni*16 + ln) & 511;
                int head = c >> 6, dd = c & 63;
                float bb = bq[c];
                #pragma unroll
                for (int reg = 0; reg < 4; ++reg) {
                    int row = m0 + wm + mi*16 + qd*4 + reg;
                    int b = row >> 10, l = row & 1023;
                    Qb[(size_t)((b*8 + head)*1024 + l)*64 + dd] =
                        acc[mi][ni][reg] + bb;
                }
            }
        }
    } else {
        const float scale = (z == 1) ? 0.125f : 1.0f;
        const float* bias = (z == 1) ? bk : bv;
        unsigned short* dst = UB2 + (size_t)(z-1) * 16 * 64 * 1024;
        #pragma unroll
        for (int mi = 0; mi < 2; ++mi) {
            #pragma unroll
            for (int ni = 0; ni < 4; ++ni) {
                int c = (n0 + ni*16 + ln) & 511;
                int head = c >> 6, dd = c & 63;
                float bb = bias[c];
                int row0 = m0 + wm + mi*16 + qd*4;
                int b = row0 >> 10, l0 = row0 & 1023;
                ushort4 o;
                o.x = f2bf((acc[mi][ni][0] + bb) * scale);
                o.y = f2bf((acc[mi][ni][1] + bb) * scale);
                o.z = f2bf((acc[mi][ni][2] + bb) * scale);
                o.w = f2bf((acc[mi][ni][3] + bb) * scale);
                *(ushort4*)&dst[((size_t)((b*8 + head)*64) + dd)*1024 + l0] = o;
            }
        }
    }
}

// ---------------------------------------------------------------------------
// K2: conv (BOTH tensors) + gate, fused (R1 verbatim; wg cast inline).
// grid (16 bh, 16 it), 256 thr.
// ---------------------------------------------------------------------------
__global__ __launch_bounds__(256) void k_conv_gate(
    const float* __restrict__ sb,
    const unsigned short* __restrict__ ub2,
    const float* __restrict__ wgw, const float* __restrict__ wg_b,
    float* __restrict__ kc, float* __restrict__ vc,
    float* __restrict__ gl)
{
    const int tid = threadIdx.x;
    const int lane = tid & 63, wave = tid >> 6;
    const int q = lane >> 4, ln = lane & 15;
    const int bh  = blockIdx.x, h = bh & 7;
    const int it  = blockIdx.y;
    const int t0  = it * 64;

    __shared__ unsigned short revf[1152];  // revf[i] = filt(1087-i), 0-padded
    __shared__ unsigned short Bk[64*72];   // k-conv B tile; later KCb (bf16)
    __shared__ unsigned short Bv[64*72];   // v-conv B tile; later Wgb

    for (int i = tid; i < 1152; i += 256) {
        int d = 1087 - i;
        revf[i] = (d >= 0 && d < 1024) ? f2bf(sb[d*8 + h]) : (unsigned short)0;
    }

    const uint4* Bg = (const uint4*)ub2;
    const size_t bk_base = (size_t)bh * 8192;          // tensor 0 (k)
    const size_t bv_base = (size_t)(16 + bh) * 8192;   // tensor 1 (v)

    floatx4 acck[4], accv[4];
    #pragma unroll
    for (int i = 0; i < 4; ++i) {
        acck[i] = (floatx4){0.f,0.f,0.f,0.f};
        accv[i] = (floatx4){0.f,0.f,0.f,0.f};
    }

    const int kend = t0 + 64;
    const int arow = 1087 - t0 - (wave*16 + ln);   // + k0 + q*8 -> frag base
    for (int k0 = 0; k0 < kend; k0 += 64) {
        #pragma unroll
        for (int s = 0; s < 2; ++s) {
            int idx = s*256 + tid;
            int r = idx >> 3, cp = idx & 7;
            *(uint4*)&Bk[r*72 + cp*8] = Bg[bk_base + (size_t)r*128 + (k0 >> 3) + cp];
            *(uint4*)&Bv[r*72 + cp*8] = Bg[bv_base + (size_t)r*128 + (k0 >> 3) + cp];
        }
        __syncthreads();                   // also covers revf on first iter
        const int ab = arow + k0 + q*8;
        short8 a0, a1;
        #pragma unroll
        for (int j = 0; j < 8; ++j) {
            a0[j] = (short)revf[ab + j];
            a1[j] = (short)revf[ab + 32 + j];
        }
        #pragma unroll
        for (int ni = 0; ni < 4; ++ni) {
            short8 kb0 = *(const short8*)&Bk[(ni*16 + ln)*72 + q*8];
            short8 kb1 = *(const short8*)&Bk[(ni*16 + ln)*72 + 32 + q*8];
            short8 vb0 = *(const short8*)&Bv[(ni*16 + ln)*72 + q*8];
            short8 vb1 = *(const short8*)&Bv[(ni*16 + ln)*72 + 32 + q*8];
            acck[ni] = __builtin_amdgcn_mfma_f32_16x16x32_bf16(a0, kb0, acck[ni], 0, 0, 0);
            acck[ni] = __builtin_amdgcn_mfma_f32_16x16x32_bf16(a1, kb1, acck[ni], 0, 0, 0);
            accv[ni] = __builtin_amdgcn_mfma_f32_16x16x32_bf16(a0, vb0, accv[ni], 0, 0, 0);
            accv[ni] = __builtin_amdgcn_mfma_f32_16x16x32_bf16(a1, vb1, accv[ni], 0, 0, 0);
        }
        __syncthreads();
    }

    // ---- epilogue: write conv outputs, stage KCb (bf16) + Wgb into LDS ----
    float* kdst = kc + (size_t)bh * 65536;
    float* vdst = vc + (size_t)bh * 65536;
    #pragma unroll
    for (int ni = 0; ni < 4; ++ni)
        #pragma unroll
        for (int reg = 0; reg < 4; ++reg) {
            int row = wave*16 + q*4 + reg;           // local row in tile
            int grow = t0 + row;
            kdst[(size_t)grow*64 + ni*16 + ln] = acck[ni][reg];
            vdst[(size_t)grow*64 + ni*16 + ln] = accv[ni][reg];
            Bk[row*72 + ni*16 + ln] = f2bf(acck[ni][reg]);
        }
    #pragma unroll
    for (int s = 0; s < 2; ++s) {          // Wgb inline cast from wg fp32
        int idx = s*256 + tid;
        int r = idx >> 3, cp = idx & 7;
        const float* ws2 = &wgw[r*64 + cp*8];
        float4 a = *(const float4*)ws2;
        float4 b = *(const float4*)(ws2 + 4);
        uint4 o;
        o.x = f2bf(a.x) | ((unsigned)f2bf(a.y) << 16);
        o.y = f2bf(a.z) | ((unsigned)f2bf(a.w) << 16);
        o.z = f2bf(b.x) | ((unsigned)f2bf(b.y) << 16);
        o.w = f2bf(b.z) | ((unsigned)f2bf(b.w) << 16);
        *(uint4*)&Bv[r*72 + cp*8] = o;
    }
    __syncthreads();

    // ---- gate MFMA: T = KCb @ Wgb^T  (K=64, two 32-chunks) ----
    floatx4 T[4];
    #pragma unroll
    for (int mt = 0; mt < 4; ++mt) T[mt] = (floatx4){0.f,0.f,0.f,0.f};
    #pragma unroll
    for (int k0g = 0; k0g < 64; k0g += 32) {
        short8 a = *(const short8*)&Bk[(wave*16 + ln)*72 + k0g + q*8];
        #pragma unroll
        for (int mt = 0; mt < 4; ++mt) {
            short8 b = *(const short8*)&Bv[(mt*16 + ln)*72 + k0g + q*8];
            T[mt] = __builtin_amdgcn_mfma_f32_16x16x32_bf16(a, b, T[mt], 0, 0, 0);
        }
    }

    // rowsum of V .* T — V comes straight from the accv registers
    float part[4] = {0.f, 0.f, 0.f, 0.f};
    #pragma unroll
    for (int mt = 0; mt < 4; ++mt)
        #pragma unroll
        for (int reg = 0; reg < 4; ++reg)
            part[reg] += T[mt][reg] * accv[mt][reg];
    #pragma unroll
    for (int reg = 0; reg < 4; ++reg) {
        part[reg] += __shfl_xor(part[reg], 1);
        part[reg] += __shfl_xor(part[reg], 2);
        part[reg] += __shfl_xor(part[reg], 4);
        part[reg] += __shfl_xor(part[reg], 8);
    }
    if (ln == 0) {
        const float wgbias = wg_b[0];
        #pragma unroll
        for (int reg = 0; reg < 4; ++reg) {
            int l = t0 + wave*16 + q*4 + reg;
            float s = part[reg] + wgbias;
            float rr = fmaxf(s, 0.0f);
            gl[bh*1024 + l] = rr*rr + 1e-5f;
        }
    }
}

// ---------------------------------------------------------------------------
// K3: A_part[slc][bh] (R1 verbatim).  grid (16 bh, 16 slices of 64), 256 thr.
// ---------------------------------------------------------------------------
__global__ __launch_bounds__(256) void k_amat(
    const float* __restrict__ kc, const float* __restrict__ vc,
    const float* __restrict__ gl, float* __restrict__ apart)
{
    const int tid = threadIdx.x, tx = tid & 15, ty = tid >> 4;
    const int lane = tid & 63, wave = tid >> 6;
    const int bh = blockIdx.x, slc = blockIdx.y;
    const float* kb = kc + (size_t)bh * 65536;
    const float* vb = vc + (size_t)bh * 65536;

    __shared__ float scanA[4], scanB[4];
    __shared__ float wfull[1024];
    __shared__ __align__(16) float vs[16][68];
    __shared__ __align__(16) float ks2[16][68];

    {
        const float4 g4 = ((const float4*)(gl + bh*1024))[tid];
        float g[4] = {g4.x, g4.y, g4.z, g4.w};
        float p[4];
        p[0]=g[0]; p[1]=p[0]+g[1]; p[2]=p[1]+g[2]; p[3]=p[2]+g[3];
        float x = p[3];
        #pragma unroll
        for (int off = 1; off < 64; off <<= 1) {
            float t = __shfl_up(x, off);
            if (lane >= off) x += t;
        }
        if (lane == 63) scanA[wave] = x;
        __syncthreads();
        float wb = 0.f;
        #pragma unroll
        for (int wv = 0; wv < 4; ++wv) wb += (wv < wave) ? scanA[wv] : 0.f;
        const float base = wb + x - p[3];
        float r[4], pr[4];
        #pragma unroll
        for (int u = 0; u < 4; ++u) r[u] = 1.0f / (base + p[u] + 1e-5f);
        pr[0]=r[0]; pr[1]=pr[0]+r[1]; pr[2]=pr[1]+r[2]; pr[3]=pr[2]+r[3];
        float y = pr[3];
        #pragma unroll
        for (int off = 1; off < 64; off <<= 1) {
            float t = __shfl_up(y, off);
            if (lane >= off) y += t;
        }
        if (lane == 63) scanB[wave] = y;
        __syncthreads();
        float rb = 0.f, Rtot = 0.f;
        #pragma unroll
        for (int wv = 0; wv < 4; ++wv) {
            rb   += (wv < wave) ? scanB[wv] : 0.f;
            Rtot += scanB[wv];
        }
        const float baser = rb + y - pr[3];
        wfull[tid*4+0] = g[0] * (Rtot - (baser + pr[0]) + r[0]);
        wfull[tid*4+1] = g[1] * (Rtot - (baser + pr[1]) + r[1]);
        wfull[tid*4+2] = g[2] * (Rtot - (baser + pr[2]) + r[2]);
        wfull[tid*4+3] = g[3] * (Rtot - (baser + pr[3]) + r[3]);
    }
    __syncthreads();

    float acc[4][4] = {};
    const float4* k4 = (const float4*)kb;
    const float4* v4 = (const float4*)vb;
    for (int j0 = slc*64; j0 < slc*64 + 64; j0 += 16) {
        {
            int r = tid >> 4, c4 = tid & 15;
            *(float4*)&vs[r][c4*4]  = v4[(size_t)(j0 + r)*16 + c4];
            *(float4*)&ks2[r][c4*4] = k4[(size_t)(j0 + r)*16 + c4];
        }
        __syncthreads();
        #pragma unroll
        for (int jj = 0; jj < 16; ++jj) {
            float wj = wfull[j0 + jj];
            float a[4];
            a[0] = vs[jj][ty*4+0]*wj; a[1] = vs[jj][ty*4+1]*wj;
            a[2] = vs[jj][ty*4+2]*wj; a[3] = vs[jj][ty*4+3]*wj;
            float4 b4 = *(const float4*)&ks2[jj][tx*4];
            float bb[4] = {b4.x, b4.y, b4.z, b4.w};
            #pragma unroll
            for (int ii = 0; ii < 4; ++ii)
                #pragma unroll
                for (int jc = 0; jc < 4; ++jc)
                    acc[ii][jc] += a[ii] * bb[jc];
        }
        __syncthreads();
    }
    float* ap = apart + (size_t)(slc*16 + bh) * 4096;
    #pragma unroll
    for (int i = 0; i < 4; ++i) {
        float4 o = { acc[i][0], acc[i][1], acc[i][2], acc[i][3] };
        *(float4*)&ap[(ty*4+i)*64 + tx*4] = o;
    }
}

// ---------------------------------------------------------------------------
// K4: ctxt = q @ A (summing 16 A-partials on load), row-normalize, bf16 -> UB.
// (R1 verbatim.)  grid (16, 16), 256 thr.
// ---------------------------------------------------------------------------
__global__ __launch_bounds__(256) void k_ctxt(
    const float* __restrict__ q, const float* __restrict__ apart,
    unsigned short* __restrict__ ub)
{
    const int tid = threadIdx.x, tx = tid & 15, ty = tid >> 4;
    const int l0 = blockIdx.x * 64;
    const int bh = blockIdx.y;
    const float* qb = q + (size_t)bh * 65536;

    __shared__ __align__(16) float qs[64][20];
    __shared__ __align__(16) float As[16][68];
    float acc[4][4] = {};
    const float4* q4 = (const float4*)qb;
    const float4* a4 = (const float4*)apart;
    for (int d0 = 0; d0 < 64; d0 += 16) {
        {
            int r = tid >> 2, c4 = tid & 3;
            float4 t = q4[(size_t)(l0 + r)*16 + (d0 >> 2) + c4];
            *(float4*)&qs[r][c4*4] = t;
        }
        {
            int r = tid >> 4, c4 = tid & 15;
            size_t o = (size_t)(d0 + r)*16 + c4;
            float4 t = a4[(size_t)(0*16 + bh)*1024 + o];
            #pragma unroll
            for (int s = 1; s < 16; ++s) {
                float4 u = a4[(size_t)(s*16 + bh)*1024 + o];
                t.x += u.x; t.y += u.y; t.z += u.z; t.w += u.w;
            }
            *(float4*)&As[r][c4*4] = t;
        }
        __syncthreads();
        float qreg[4][16];
        #pragma unroll
        for (int i = 0; i < 4; ++i)
            #pragma unroll
            for (int c = 0; c < 4; ++c) {
                float4 t = *(const float4*)&qs[ty*4+i][c*4];
                qreg[i][c*4+0] = t.x; qreg[i][c*4+1] = t.y;
                qreg[i][c*4+2] = t.z; qreg[i][c*4+3] = t.w;
            }
        #pragma unroll
        for (int dd = 0; dd < 16; ++dd) {
            float4 b4 = *(const float4*)&As[dd][tx*4];
            float bb[4] = {b4.x, b4.y, b4.z, b4.w};
            #pragma unroll
            for (int ii = 0; ii < 4; ++ii)
                #pragma unroll
                for (int jj = 0; jj < 4; ++jj)
                    acc[ii][jj] += qreg[ii][dd] * bb[jj];
        }
        __syncthreads();
    }
    __shared__ float red[64][17];
    __shared__ float nrm[64];
    #pragma unroll
    for (int i = 0; i < 4; ++i) {
        red[ty*4+i][tx] = acc[i][0]*acc[i][0] + acc[i][1]*acc[i][1]
                        + acc[i][2]*acc[i][2] + acc[i][3]*acc[i][3];
    }
    __syncthreads();
    if (tid < 64) {
        float s = 0.0f;
        #pragma unroll
        for (int t = 0; t < 16; ++t) s += red[tid][t];
        nrm[tid] = fmaxf(sqrtf(s), 1e-5f);
    }
    __syncthreads();
    const int b = bh >> 3, hd = bh & 7;
    #pragma unroll
    for (int i = 0; i < 4; ++i) {
        int lr = ty*4 + i;
        float inv = 1.0f / nrm[lr];
        ushort4 o;
        o.x = f2bf(acc[i][0]*inv); o.y = f2bf(acc[i][1]*inv);
        o.z = f2bf(acc[i][2]*inv); o.w = f2bf(acc[i][3]*inv);
        *(ushort4*)&ub[(size_t)(b*1024 + l0 + lr)*512 + hd*64 + tx*4] = o;
    }
}

// ---------------------------------------------------------------------------
// K5: out = UB[2048][512](bf16) @ WOT^T + bo.  256 even 64x64 tiles.
// ---------------------------------------------------------------------------
__global__ __launch_bounds__(256) void k_out(
    const unsigned short* __restrict__ ub, const unsigned short* __restrict__ woT,
    const float* __restrict__ bo, float* __restrict__ out)
{
    const int tid = threadIdx.x;
    const int lane = tid & 63, wave = tid >> 6;
    const int qd = lane >> 4, ln = lane & 15;
    const int m0 = (blockIdx.x >> 3) * 64;
    const int n0 = (blockIdx.x & 7) * 64;

    __shared__ unsigned short As[64*72];
    __shared__ unsigned short Bs[64*72];

    floatx4 acc[4];
    #pragma unroll
    for (int i = 0; i < 4; ++i) acc[i] = (floatx4){0.f,0.f,0.f,0.f};

    const uint4* Ag = (const uint4*)ub;
    const uint4* Bg = (const uint4*)woT;
    for (int k0 = 0; k0 < 512; k0 += 64) {
        #pragma unroll
        for (int s = 0; s < 2; ++s) {
            int idx = s*256 + tid;
            int r = idx >> 3, cp = idx & 7;
            *(uint4*)&As[r*72 + cp*8] = Ag[(size_t)(m0 + r)*64 + (k0 >> 3) + cp];
            *(uint4*)&Bs[r*72 + cp*8] = Bg[(size_t)(n0 + r)*64 + (k0 >> 3) + cp];
        }
        __syncthreads();
        short8 af0 = *(const short8*)&As[(wave*16 + ln)*72 + qd*8];
        short8 af1 = *(const short8*)&As[(wave*16 + ln)*72 + 32 + qd*8];
        #pragma unroll
        for (int ni = 0; ni < 4; ++ni) {
            short8 bf0 = *(const short8*)&Bs[(ni*16 + ln)*72 + qd*8];
            short8 bf1 = *(const short8*)&Bs[(ni*16 + ln)*72 + 32 + qd*8];
            acc[ni] = __builtin_amdgcn_mfma_f32_16x16x32_bf16(af0, bf0, acc[ni], 0, 0, 0);
            acc[ni] = __builtin_amdgcn_mfma_f32_16x16x32_bf16(af1, bf1, acc[ni], 0, 0, 0);
        }
        __syncthreads();
    }

    #pragma unroll
    for (int ni = 0; ni < 4; ++ni) {
        int gcol = n0 + ni*16 + ln;
        float bb = bo[gcol];
        #pragma unroll
        for (int reg = 0; reg < 4; ++reg) {
            int row = m0 + wave*16 + qd*4 + reg;
            out[(size_t)row*512 + gcol] = acc[ni][reg] + bb;
        }
    }
}

extern "C" void kernel_launch(void* const* d_in, const int* in_sizes, int n_in,
                              void* d_out, int out_size, void* d_ws, size_t ws_size,
                              hipStream_t stream)
{
    const float* x   = (const float*)d_in[0];
    const float* sb  = (const float*)d_in[1];
    const float* wq  = (const float*)d_in[2];
    const float* bq  = (const float*)d_in[3];
    const float* wk  = (const float*)d_in[4];
    const float* bk  = (const float*)d_in[5];
    const float* wv  = (const float*)d_in[6];
    const float* bv  = (const float*)d_in[7];
    const float* wo  = (const float*)d_in[8];
    const float* bo  = (const float*)d_in[9];
    const float* wg  = (const float*)d_in[10];
    const float* wgb = (const float*)d_in[11];
    float* out = (float*)d_out;
    float* ws  = (float*)d_ws;

    // workspace layout (float offsets)
    float* Qb  = ws;                        // 1048576 f32
    float* KC  = Qb + 1048576;              // 1048576
    float* VC  = KC + 1048576;              // 1048576
    float* GL  = VC + 1048576;              // 16384
    float* AP  = GL + 16384;                // 1048576
    float* fp  = AP + 1048576;
    unsigned short* WOT = (unsigned short*)fp;              // 262144 u16
    unsigned short* UB  = WOT + 262144;                     // 1048576
    unsigned short* UB2 = UB  + 1048576;                    // 2097152

    k_qkv      <<<dim3(24, 16), 256, 0, stream>>>(x, wq, wk, wv, wo,
                                                  bq, bk, bv, WOT, Qb, UB2);
    k_conv_gate<<<dim3(16, 16), 256, 0, stream>>>(sb, UB2, wg, wgb, KC, VC, GL);
    k_amat     <<<dim3(16, 16), 256, 0, stream>>>(KC, VC, GL, AP);
    k_ctxt     <<<dim3(16, 16), 256, 0, stream>>>(Qb, AP, UB);
    k_out      <<<dim3(256),    256, 0, stream>>>(UB, WOT, bo, out);
}